// Round 2
// baseline (231.794 us; speedup 1.0000x reference)
//
#include <hip/hip_runtime.h>
#include <math.h>

#define NFEAT 128
#define NHID 256

typedef __attribute__((ext_vector_type(8))) short short8;
typedef __attribute__((ext_vector_type(4))) float f32x4;
typedef __attribute__((ext_vector_type(2))) float f32x2;

__device__ inline unsigned short f2bf(float f) {
  unsigned u = __float_as_uint(f);
  u += 0x7fffu + ((u >> 16) & 1u);
  return (unsigned short)(u >> 16);
}
__device__ inline float bflo(unsigned u) { return __uint_as_float(u << 16); }
__device__ inline float bfhi(unsigned u) { return __uint_as_float(u & 0xffff0000u); }

// ---- W pack helper: bf16 B-fragment layout for 16x16x32 MFMA ----
__device__ inline void packOne(const float* __restrict__ W,
                               unsigned short* __restrict__ Wp, int idx, int KS,
                               int OUT) {
  int lane = idx & 63;
  int t = idx >> 6;
  int ks = t % KS;
  int nt = t / KS;
  int n = nt * 16 + (lane & 15);
  int k0 = ks * 32 + (lane >> 4) * 8;
  unsigned short v[8];
#pragma unroll
  for (int j = 0; j < 8; j++) v[j] = f2bf(W[(size_t)(k0 + j) * OUT + n]);
  *reinterpret_cast<short8*>(Wp + (size_t)idx * 8) =
      *reinterpret_cast<short8*>(v);
}

// ---- deg count (global atomics) + W pack on trailing blocks ----
__global__ __launch_bounds__(256) void k_deg_pack(
    const int* __restrict__ col, int* __restrict__ deg, int nE, int nEB,
    const float* __restrict__ W1, const float* __restrict__ W2,
    unsigned short* __restrict__ W1p, unsigned short* __restrict__ W2p) {
  if (blockIdx.x >= nEB) {  // 32 pack blocks x 256 = 8192 items
    int idx = (blockIdx.x - nEB) * 256 + threadIdx.x;
    if (idx < 4096) packOne(W1, W1p, idx, 4, 256);
    else packOne(W2, W2p, idx - 4096, 8, 128);
    return;
  }
  int i = blockIdx.x * 256 + threadIdx.x;
  if (i < nE) atomicAdd(&deg[col[i]], 1);
}

// ---- scan phase 1: per-256-chunk sums of (deg+1); last block: head const ----
__global__ __launch_bounds__(256) void k_bsum(const int* __restrict__ a,
                                              int* __restrict__ psum, int S,
                                              const float* __restrict__ b2,
                                              const float* __restrict__ Wl,
                                              const float* __restrict__ bl,
                                              float* __restrict__ Cbuf) {
  int t = threadIdx.x;
  if (blockIdx.x == gridDim.x - 1) {  // C = b2.(Wl_lo+Wl_hi) + bl
    float v = (t < 128) ? b2[t] * (Wl[t] + Wl[128 + t]) : 0.f;
#pragma unroll
    for (int o = 32; o; o >>= 1) v += __shfl_down(v, o);
    __shared__ float fw[4];
    if ((t & 63) == 0) fw[t >> 6] = v;
    __syncthreads();
    if (t == 0) Cbuf[0] = fw[0] + fw[1] + fw[2] + fw[3] + bl[0];
    return;
  }
  int i = blockIdx.x * 256 + t;
  int v = (i < S) ? a[i] + 1 : 0;
#pragma unroll
  for (int o = 32; o; o >>= 1) v += __shfl_down(v, o);
  __shared__ int ws[4];
  if ((t & 63) == 0) ws[t >> 6] = v;
  __syncthreads();
  if (t == 0) psum[blockIdx.x] = ws[0] + ws[1] + ws[2] + ws[3];
}

// ---- scan phase 2: redundant base reduce + local scan; emits offs, cur,
//      dinv and the self-loop edge ----
__global__ __launch_bounds__(256) void k_scan(const int* __restrict__ deg,
                                              const int* __restrict__ psum,
                                              int* __restrict__ offs,
                                              int* __restrict__ cur,
                                              float* __restrict__ dinv,
                                              int* __restrict__ ebuf, int n) {
  __shared__ int sh[256];
  __shared__ int ws[4];
  int t = threadIdx.x;
  int b = blockIdx.x;
  int partial = 0;
  for (int i = t; i < b; i += 256) partial += psum[i];
#pragma unroll
  for (int o = 32; o; o >>= 1) partial += __shfl_down(partial, o);
  if ((t & 63) == 0) ws[t >> 6] = partial;
  int i = b * 256 + t;
  int d = (i < n) ? deg[i] + 1 : 0;  // +1 self loop
  sh[t] = d;
  __syncthreads();
  int base = ws[0] + ws[1] + ws[2] + ws[3];
  for (int o = 1; o < 256; o <<= 1) {
    int u = (t >= o) ? sh[t - o] : 0;
    __syncthreads();
    sh[t] += u;
    __syncthreads();
  }
  if (i < n) {
    int off = base + sh[t] - d;  // exclusive prefix
    offs[i] = off;
    cur[i] = off + 1;        // real edges start after the self slot
    dinv[i] = rsqrtf((float)d);
    ebuf[off] = i;           // self edge
    if (i == n - 1) offs[n] = off + d;
  }
}

// ---- edge fill (atomic slot claim) merged with feat->bf16 convert ----
// xs[node][f] = bf16(dinv[node] * X[node][f])   (row-major, 256B rows)
__global__ __launch_bounds__(256) void k_fill_cvt(
    const int* __restrict__ row, const int* __restrict__ col,
    int* __restrict__ cur, int* __restrict__ ebuf,
    const float* __restrict__ feat, const float* __restrict__ dinv,
    unsigned short* __restrict__ xs, int nE, int nItems) {
  int i = blockIdx.x * 256 + threadIdx.x;
  if (i < nE) {
    int c = col[i];
    int pos = atomicAdd(&cur[c], 1);
    ebuf[pos] = row[i];
  }
  if (i < nItems) {  // nItems = n*32 float4 chunks
    int node = i >> 5;
    float d = dinv[node];
    float4 v = reinterpret_cast<const float4*>(feat)[(size_t)i];
    unsigned short o[4] = {f2bf(v.x * d), f2bf(v.y * d), f2bf(v.z * d),
                           f2bf(v.w * d)};
    reinterpret_cast<ushort4*>(xs)[(size_t)i] = *reinterpret_cast<ushort4*>(o);
  }
}

// ---------------- bf16 gather-aggregate, node-major -------------------------
// wave = 1 node; lane l: edge slot g=l>>4, 16B chunk c=l&15. self is a real
// edge, so no special case. 2 gathers in flight per lane.
// OUT[i] = bf16( dinv[i] * sum_{e in offs[i]..offs[i+1]} xs[ebuf[e]] )
__global__ __launch_bounds__(256) void k_agg_bf(
    const char* __restrict__ Gb, const int* __restrict__ offs,
    const int* __restrict__ ebuf, const float* __restrict__ dinv,
    char* __restrict__ Ob, int n) {
  int node = blockIdx.x * 4 + (threadIdx.x >> 6);
  if (node >= n) return;
  int lane = threadIdx.x & 63;
  int g = lane >> 4;
  unsigned cb = (unsigned)(lane & 15) << 4;  // chunk byte offset in 256B row
  int beg = offs[node], end = offs[node + 1];
  f32x2 acc[4] = {};
  int e = beg + g;
  for (; e + 4 < end; e += 8) {  // two independent gathers in flight
    int i0 = ebuf[e], i1 = ebuf[e + 4];
    uint4 v0 = *reinterpret_cast<const uint4*>(Gb + (((unsigned)i0 << 8) | cb));
    uint4 v1 = *reinterpret_cast<const uint4*>(Gb + (((unsigned)i1 << 8) | cb));
    acc[0] += (f32x2){bflo(v0.x), bfhi(v0.x)};
    acc[1] += (f32x2){bflo(v0.y), bfhi(v0.y)};
    acc[2] += (f32x2){bflo(v0.z), bfhi(v0.z)};
    acc[3] += (f32x2){bflo(v0.w), bfhi(v0.w)};
    acc[0] += (f32x2){bflo(v1.x), bfhi(v1.x)};
    acc[1] += (f32x2){bflo(v1.y), bfhi(v1.y)};
    acc[2] += (f32x2){bflo(v1.z), bfhi(v1.z)};
    acc[3] += (f32x2){bflo(v1.w), bfhi(v1.w)};
  }
  if (e < end) {
    int i0 = ebuf[e];
    uint4 v0 = *reinterpret_cast<const uint4*>(Gb + (((unsigned)i0 << 8) | cb));
    acc[0] += (f32x2){bflo(v0.x), bfhi(v0.x)};
    acc[1] += (f32x2){bflo(v0.y), bfhi(v0.y)};
    acc[2] += (f32x2){bflo(v0.z), bfhi(v0.z)};
    acc[3] += (f32x2){bflo(v0.w), bfhi(v0.w)};
  }
#pragma unroll
  for (int j = 0; j < 4; j++) {  // fold 4 edge-groups into lanes 0..15
    acc[j].x += __shfl_down(acc[j].x, 32);
    acc[j].y += __shfl_down(acc[j].y, 32);
    acc[j].x += __shfl_down(acc[j].x, 16);
    acc[j].y += __shfl_down(acc[j].y, 16);
  }
  if (g == 0) {
    float d = dinv[node];
    unsigned o[4];
#pragma unroll
    for (int k = 0; k < 4; k++)
      o[k] = (unsigned)f2bf(acc[k].x * d) |
             ((unsigned)f2bf(acc[k].y * d) << 16);
    *reinterpret_cast<uint4*>(Ob + (((unsigned)node << 8) | cb)) =
        *reinterpret_cast<uint4*>(o);
  }
}

// ---------------- fused double GEMM + head projection, 32-row tiles ---------
// per block (4 waves): rows r0..r0+31.
//   phase A: h1 = relu(z@W1 + b1)  [32x256] -> LDS (row stride 264 shorts)
//   phase B: g2' = (h1@W2)*dinv    [32x128] -> projected: p = {g2'.Wl_lo, g2'.Wl_hi}
// g2 is NEVER materialized. caller gives 16-row slack in z/dinv/p.
__global__ __launch_bounds__(256) void k_mfma_fused(
    const unsigned short* __restrict__ A, const unsigned short* __restrict__ B1p,
    const unsigned short* __restrict__ B2p, const float* __restrict__ b1,
    const float* __restrict__ dinv, const float* __restrict__ Wl,
    float* __restrict__ P) {
  __shared__ unsigned short sh1[32 * 264];  // +8 pad: 2-way LDS conflicts only
  __shared__ float pacc[32][2];
  int rt0 = blockIdx.x * 2;
  int wave = threadIdx.x >> 6;
  int lane = threadIdx.x & 63;
  int quad = lane >> 4;
  int mrow0 = rt0 * 16 + (lane & 15);
  if (threadIdx.x < 64) pacc[threadIdx.x >> 1][threadIdx.x & 1] = 0.f;

  // ---- phase A: cols wave*64 .. wave*64+63 of h1, two 16-row tiles ----
  f32x4 acc[2][4] = {};
  const short8* Ap0 =
      reinterpret_cast<const short8*>(A + (size_t)mrow0 * NFEAT + quad * 8);
  const short8* Ap1 = reinterpret_cast<const short8*>(
      A + (size_t)(mrow0 + 16) * NFEAT + quad * 8);
#pragma unroll
  for (int ks = 0; ks < 4; ks++) {
    short8 a0 = Ap0[ks * 4];
    short8 a1 = Ap1[ks * 4];
#pragma unroll
    for (int ct = 0; ct < 4; ct++) {
      int nt = wave * 4 + ct;
      short8 b = *reinterpret_cast<const short8*>(
          B1p + ((size_t)(nt * 4 + ks) * 64 + lane) * 8);
      acc[0][ct] = __builtin_amdgcn_mfma_f32_16x16x32_bf16(a0, b, acc[0][ct], 0, 0, 0);
      acc[1][ct] = __builtin_amdgcn_mfma_f32_16x16x32_bf16(a1, b, acc[1][ct], 0, 0, 0);
    }
  }
#pragma unroll
  for (int ct = 0; ct < 4; ct++) {
    int c = (wave * 4 + ct) * 16 + (lane & 15);
    float bv = b1[c];
#pragma unroll
    for (int rg = 0; rg < 2; rg++)
#pragma unroll
      for (int i = 0; i < 4; i++) {
        float v = fmaxf(acc[rg][ct][i] + bv, 0.f);
        sh1[(rg * 16 + quad * 4 + i) * 264 + c] = f2bf(v);
      }
  }
  __syncthreads();

  // ---- phase B: cols wave*32 .. wave*32+31, K=256 from LDS; project to p ----
  f32x4 acc2[2][2] = {};
  const unsigned short* a2_0 = sh1 + (size_t)(lane & 15) * 264 + quad * 8;
  const unsigned short* a2_1 = sh1 + (size_t)(16 + (lane & 15)) * 264 + quad * 8;
#pragma unroll
  for (int ks = 0; ks < 8; ks++) {
    short8 a0 = *reinterpret_cast<const short8*>(a2_0 + ks * 32);
    short8 a1 = *reinterpret_cast<const short8*>(a2_1 + ks * 32);
#pragma unroll
    for (int ct = 0; ct < 2; ct++) {
      int nt = wave * 2 + ct;
      short8 b = *reinterpret_cast<const short8*>(
          B2p + ((size_t)(nt * 8 + ks) * 64 + lane) * 8);
      acc2[0][ct] = __builtin_amdgcn_mfma_f32_16x16x32_bf16(a0, b, acc2[0][ct], 0, 0, 0);
      acc2[1][ct] = __builtin_amdgcn_mfma_f32_16x16x32_bf16(a1, b, acc2[1][ct], 0, 0, 0);
    }
  }
  float p1[2][4] = {}, p2[2][4] = {};
#pragma unroll
  for (int rg = 0; rg < 2; rg++) {
    int r0 = (rt0 + rg) * 16 + quad * 4;
    float dv[4];
#pragma unroll
    for (int i = 0; i < 4; i++) dv[i] = dinv[r0 + i];
#pragma unroll
    for (int ct = 0; ct < 2; ct++) {
      int c = (wave * 2 + ct) * 16 + (lane & 15);
      float wl1 = Wl[c], wl2 = Wl[128 + c];
#pragma unroll
      for (int i = 0; i < 4; i++) {
        float v = acc2[rg][ct][i] * dv[i];
        p1[rg][i] = fmaf(v, wl1, p1[rg][i]);
        p2[rg][i] = fmaf(v, wl2, p2[rg][i]);
      }
    }
  }
  // reduce over the 16 lanes of this quad (cols), then cross-wave via LDS
#pragma unroll
  for (int rg = 0; rg < 2; rg++)
#pragma unroll
    for (int i = 0; i < 4; i++) {
#pragma unroll
      for (int o = 8; o; o >>= 1) {
        p1[rg][i] += __shfl_xor(p1[rg][i], o);
        p2[rg][i] += __shfl_xor(p2[rg][i], o);
      }
    }
  if ((lane & 15) == 0) {
#pragma unroll
    for (int rg = 0; rg < 2; rg++)
#pragma unroll
      for (int i = 0; i < 4; i++) {
        int row = rg * 16 + quad * 4 + i;
        atomicAdd(&pacc[row][0], p1[rg][i]);
        atomicAdd(&pacc[row][1], p2[rg][i]);
      }
  }
  __syncthreads();
  if (threadIdx.x < 64) {
    int row = threadIdx.x >> 1, comp = threadIdx.x & 1;
    P[(size_t)(rt0 * 16 + row) * 2 + comp] = pacc[row][comp];
  }
}

// ---------------- scalar aggregation of projections ----------------
// 4 lanes per node (64 nodes/block): q[i] = dinv[i]*sum_{e} p[ebuf[e]]
// (self is a real edge in ebuf)
__global__ __launch_bounds__(256) void k_agg_s(const float2* __restrict__ p,
                                               const int* __restrict__ offs,
                                               const int* __restrict__ ebuf,
                                               const float* __restrict__ dinv,
                                               float2* __restrict__ q, int n) {
  int i = blockIdx.x * 64 + (threadIdx.x >> 2);
  if (i >= n) return;
  int sub = threadIdx.x & 3;
  int beg = offs[i], end = offs[i + 1];
  float sx = 0.f, sy = 0.f;
  for (int e = beg + sub; e < end; e += 4) {
    float2 v = p[ebuf[e]];
    sx += v.x;
    sy += v.y;
  }
  sx += __shfl_down(sx, 2);
  sy += __shfl_down(sy, 2);
  sx += __shfl_down(sx, 1);
  sy += __shfl_down(sy, 1);
  if (sub == 0) {
    float d = dinv[i];
    q[i] = make_float2(sx * d, sy * d);
  }
}

// ---------------- link head: sigmoid(q1[m0] + q2[m1] + C) ----------------
__global__ __launch_bounds__(256) void k_head2(const float2* __restrict__ q,
                                               const int* __restrict__ mask,
                                               const float* __restrict__ Cbuf,
                                               float* __restrict__ out, int P) {
  int p = blockIdx.x * 256 + threadIdx.x;
  if (p >= P) return;
  int m0 = mask[2 * p], m1 = mask[2 * p + 1];
  float s = q[m0].x + q[m1].y + Cbuf[0];
  out[p] = 1.0f / (1.0f + expf(-s));
}

extern "C" void kernel_launch(void* const* d_in, const int* in_sizes, int n_in,
                              void* d_out, int out_size, void* d_ws,
                              size_t ws_size, hipStream_t stream) {
  const int* edge = (const int*)d_in[0];
  const float* feat = (const float*)d_in[1];
  const int* mask = (const int*)d_in[2];
  const float* W1 = (const float*)d_in[3];
  const float* b1 = (const float*)d_in[4];
  const float* W2 = (const float*)d_in[5];
  const float* b2 = (const float*)d_in[6];
  const float* Wl = (const float*)d_in[7];
  const float* bl = (const float*)d_in[8];
  float* out = (float*)d_out;

  const int E = in_sizes[0] / 2;
  const int N = in_sizes[1] / NFEAT;
  const int P = in_sizes[2] / 2;
  const int* rowp = edge;
  const int* colp = edge + E;
  const int nrt = N / 16;              // 3125 for N=50000
  const int nS = (N + 255) / 256;      // 196 scan chunks (<= 1024 required)
  const int nEB = (E + 255) / 256;     // 3125 edge blocks
  const int nItems = N * (NFEAT / 4);  // float4 chunks for cvt
  const int nFC = max(nEB, (nItems + 255) / 256);

  auto aln = [](size_t x) { return (x + 255) & ~(size_t)255; };
  const size_t rowSlack = (size_t)16 * NFEAT * 2;  // 16-row tail slack
  char* w = (char*)d_ws;
  int* deg = (int*)w;              w += aln((size_t)N * 4);
  int* cur = (int*)w;              w += aln((size_t)N * 4);
  int* psum = (int*)w;             w += aln((size_t)1024 * 4);
  float* Cbuf = (float*)w;         w += aln(256);
  int* offs = (int*)w;             w += aln((size_t)(N + 1) * 4);
  int* ebuf = (int*)w;             w += aln((size_t)(E + N) * 4);
  float* dinv = (float*)w;         w += aln((size_t)N * 4 + 1024);
  unsigned short* xs = (unsigned short*)w;  w += aln((size_t)N * NFEAT * 2);
  unsigned short* z = (unsigned short*)w;   w += aln((size_t)N * NFEAT * 2 + rowSlack);
  float* p = (float*)w;            w += aln((size_t)(N + 32) * 8);
  float2* q = (float2*)w;          w += aln((size_t)N * 8);
  unsigned short* W1p = (unsigned short*)w; w += aln((size_t)NFEAT * NHID * 2);
  unsigned short* W2p = (unsigned short*)w; w += aln((size_t)NHID * NFEAT * 2);

  // ---- CSR build: atomic deg -> scan -> atomic fill (+ W pack, + cvt) ----
  hipMemsetAsync(deg, 0, (size_t)N * 4, stream);
  k_deg_pack<<<nEB + 32, 256, 0, stream>>>(colp, deg, E, nEB, W1, W2, W1p,
                                           W2p);
  k_bsum<<<nS + 1, 256, 0, stream>>>(deg, psum, N, b2, Wl, bl, Cbuf);
  k_scan<<<nS, 256, 0, stream>>>(deg, psum, offs, cur, dinv, ebuf, N);
  k_fill_cvt<<<nFC, 256, 0, stream>>>(rowp, colp, cur, ebuf, feat, dinv, xs, E,
                                      nItems);
  // z = bf16(dinv .* sum_in xs)                  [= A_norm @ X, bf16]
  k_agg_bf<<<(N + 3) / 4, 256, 0, stream>>>((const char*)xs, offs, ebuf, dinv,
                                            (char*)z, N);
  // p[i] = {(dinv_i*(relu(z@W1+b1)@W2)_i) . Wl_lo, . Wl_hi}  (g2 not stored)
  k_mfma_fused<<<(nrt + 1) / 2, 256, 0, stream>>>(z, W1p, W2p, b1, dinv, Wl, p);
  // q[i] = dinv[i]*sum p[src]  (self included in ebuf)
  k_agg_s<<<(N + 63) / 64, 256, 0, stream>>>((const float2*)p, offs, ebuf,
                                             dinv, q, N);
  // head: out = sigmoid(q1[m0] + q2[m1] + C)
  k_head2<<<(P + 255) / 256, 256, 0, stream>>>(q, mask, Cbuf, out, P);
}

// Round 3
// 180.703 us; speedup vs baseline: 1.2827x; 1.2827x over previous
//
#include <hip/hip_runtime.h>
#include <math.h>

#define NFEAT 128
#define NHID 256
#define NBLK 128  // partition blocks; (block,bucket) segment avg = 8 edges = 32B

typedef __attribute__((ext_vector_type(8))) short short8;
typedef __attribute__((ext_vector_type(4))) float f32x4;
typedef __attribute__((ext_vector_type(2))) float f32x2;

__device__ inline unsigned short f2bf(float f) {
  unsigned u = __float_as_uint(f);
  u += 0x7fffu + ((u >> 16) & 1u);
  return (unsigned short)(u >> 16);
}
__device__ inline float bflo(unsigned u) { return __uint_as_float(u << 16); }
__device__ inline float bfhi(unsigned u) { return __uint_as_float(u & 0xffff0000u); }

// ============ CSR build: deterministic 2-pass partition, no global atomics ==
// bucket = dest >> 6 (64 nodes/bucket); needs N <= 65536 (16-bit packing)

// ---- per-(block,bucket) histogram (blocks 0..NBLK-1) + W-pack (blocks >= NBLK)
__device__ inline void packOne(const float* __restrict__ W,
                               unsigned short* __restrict__ Wp, int idx, int KS,
                               int OUT) {
  int lane = idx & 63;
  int t = idx >> 6;
  int ks = t % KS;
  int nt = t / KS;
  int n = nt * 16 + (lane & 15);
  int k0 = ks * 32 + (lane >> 4) * 8;
  unsigned short v[8];
#pragma unroll
  for (int j = 0; j < 8; j++) v[j] = f2bf(W[(size_t)(k0 + j) * OUT + n]);
  *reinterpret_cast<short8*>(Wp + (size_t)idx * 8) =
      *reinterpret_cast<short8*>(v);
}

__global__ __launch_bounds__(1024) void k_hist_pack(
    const int* __restrict__ col, int* __restrict__ hist2d, int nE, int nb,
    const float* __restrict__ W1, const float* __restrict__ W2,
    unsigned short* __restrict__ W1p, unsigned short* __restrict__ W2p) {
  if (blockIdx.x >= NBLK) {  // pack blocks: 8 x 1024 threads = 8192 items
    int idx = (blockIdx.x - NBLK) * 1024 + threadIdx.x;
    if (idx < 4096) packOne(W1, W1p, idx, 4, 256);
    else packOne(W2, W2p, idx - 4096, 8, 128);
    return;
  }
  __shared__ int h[1024];
  for (int i = threadIdx.x; i < nb; i += 1024) h[i] = 0;
  __syncthreads();
  int chunk = (nE + NBLK - 1) / NBLK;
  int beg = blockIdx.x * chunk, end = min(beg + chunk, nE);
  for (int e = beg + threadIdx.x; e < end; e += 1024)
    atomicAdd(&h[col[e] >> 6], 1);
  __syncthreads();
  for (int i = threadIdx.x; i < nb; i += 1024)
    hist2d[i * NBLK + blockIdx.x] = h[i];
}

// ---- scan phase 1: per-256-chunk sums; last block computes head constant ----
__global__ __launch_bounds__(256) void k_bsum(const int* __restrict__ a,
                                              int* __restrict__ psum, int S,
                                              const float* __restrict__ b2,
                                              const float* __restrict__ Wl,
                                              const float* __restrict__ bl,
                                              float* __restrict__ Cbuf) {
  int t = threadIdx.x;
  if (blockIdx.x == gridDim.x - 1) {  // C = b2.(Wl_lo+Wl_hi) + bl
    float v = (t < 128) ? b2[t] * (Wl[t] + Wl[128 + t]) : 0.f;
#pragma unroll
    for (int o = 32; o; o >>= 1) v += __shfl_down(v, o);
    __shared__ float fw[4];
    if ((t & 63) == 0) fw[t >> 6] = v;
    __syncthreads();
    if (t == 0) Cbuf[0] = fw[0] + fw[1] + fw[2] + fw[3] + bl[0];
    return;
  }
  int i = blockIdx.x * 256 + t;
  int v = (i < S) ? a[i] : 0;
#pragma unroll
  for (int o = 32; o; o >>= 1) v += __shfl_down(v, o);
  __shared__ int ws[4];
  if ((t & 63) == 0) ws[t >> 6] = v;
  __syncthreads();
  if (t == 0) psum[blockIdx.x] = ws[0] + ws[1] + ws[2] + ws[3];
}

// ---- scan phase 2+3 merged: each block redundantly reduces psum[0..b) for
//      its base, then scans its own 256 elements ----
__global__ __launch_bounds__(256) void k_s3m(const int* __restrict__ a,
                                             const int* __restrict__ psum,
                                             int* __restrict__ out, int S) {
  __shared__ int sh[256];
  __shared__ int ws[4];
  int t = threadIdx.x;
  int b = blockIdx.x;
  int partial = 0;
  for (int i = t; i < b; i += 256) partial += psum[i];
#pragma unroll
  for (int o = 32; o; o >>= 1) partial += __shfl_down(partial, o);
  if ((t & 63) == 0) ws[t >> 6] = partial;
  int i = b * 256 + t;
  int d = (i < S) ? a[i] : 0;
  sh[t] = d;
  __syncthreads();
  int base = ws[0] + ws[1] + ws[2] + ws[3];
  for (int o = 1; o < 256; o <<= 1) {
    int u = (t >= o) ? sh[t - o] : 0;
    __syncthreads();
    sh[t] += u;
    __syncthreads();
  }
  if (i < S) out[i] = base + sh[t] - d;
}

// ---- partition: each block writes its own contiguous segments ----
__global__ __launch_bounds__(1024) void k_part2(const int* __restrict__ row,
                                                const int* __restrict__ col,
                                                const int* __restrict__ sbase,
                                                unsigned* __restrict__ tmp,
                                                int nE, int nb) {
  __shared__ int cur[1024];
  for (int i = threadIdx.x; i < nb; i += 1024)
    cur[i] = sbase[i * NBLK + blockIdx.x];
  __syncthreads();
  int chunk = (nE + NBLK - 1) / NBLK;
  int beg = blockIdx.x * chunk, end = min(beg + chunk, nE);
  for (int e = beg + threadIdx.x; e < end; e += 1024) {
    int c = col[e];
    int pos = atomicAdd(&cur[c >> 6], 1);
    tmp[pos] = ((unsigned)(c & 63) << 16) | (unsigned)row[e];
  }
}

// ---- per-bucket counting sort -> ebuf + offs + dinv; also cvt this bucket's
//      64 feature rows: xs = bf16(dinv[row] * X) ----
__global__ __launch_bounds__(256) void k_bsort_cvt(
    const unsigned* __restrict__ tmp, const int* __restrict__ sbase,
    int* __restrict__ ebuf, int* __restrict__ offs, float* __restrict__ dinv,
    const float* __restrict__ feat, unsigned short* __restrict__ xs, int n,
    int nE, int nb) {
  __shared__ int bins[64], cur[64];
  __shared__ float sdinv[64];
  int b = blockIdx.x;
  int beg = sbase[b * NBLK];
  int end = (b == nb - 1) ? nE : sbase[(b + 1) * NBLK];
  int t = threadIdx.x;
  if (t == 0 && b == nb - 1) offs[n] = nE;
  if (t < 64) bins[t] = 0;
  __syncthreads();
  for (int i = beg + t; i < end; i += 256) atomicAdd(&bins[tmp[i] >> 16], 1);
  __syncthreads();
  if (t < 64) {  // wave 0: exclusive scan of 64 bins via shfl
    int v = bins[t];
    int s = v;
#pragma unroll
    for (int o = 1; o < 64; o <<= 1) {
      int u = __shfl_up(s, o);
      if (t >= o) s += u;
    }
    int off = beg + s - v;
    cur[t] = off;
    float dv = rsqrtf((float)(v + 1));  // +1 self loop
    sdinv[t] = dv;
    int node = b * 64 + t;
    if (node < n) {
      offs[node] = off;
      dinv[node] = dv;
    }
  }
  __syncthreads();
  for (int i = beg + t; i < end; i += 256) {
    unsigned p = tmp[i];
    int pos = atomicAdd(&cur[p >> 16], 1);
    ebuf[pos] = (int)(p & 0xffffu);
  }
  // cvt: 64 rows x 32 float4
  for (int i = t; i < 64 * 32; i += 256) {
    int r = i >> 5;
    int node = b * 64 + r;
    if (node >= n) break;
    float d = sdinv[r];
    float4 v = reinterpret_cast<const float4*>(feat)[(size_t)node * 32 + (i & 31)];
    unsigned short o[4] = {f2bf(v.x * d), f2bf(v.y * d), f2bf(v.z * d),
                           f2bf(v.w * d)};
    reinterpret_cast<ushort4*>(xs)[(size_t)node * 32 + (i & 31)] =
        *reinterpret_cast<ushort4*>(o);
  }
}

// ======== FUSED: gather-aggregate (phase 0) + double GEMM + projection ======
// Block = 32 output rows (2 row-tiles). Phase 0: each wave aggregates 8 of the
// block's rows from xs (4 edge-slots x 16 chunks, 2 gathers in flight) and
// writes bf16 rows into XOR-swizzled LDS (z never hits HBM). Phase A/B: the
// round-0 double GEMM + head projection, A-operand read from LDS.
__global__ __launch_bounds__(256) void k_fused(
    const char* __restrict__ Gb, const int* __restrict__ offs,
    const int* __restrict__ ebuf, const float* __restrict__ dinv,
    const unsigned short* __restrict__ B1p, const unsigned short* __restrict__ B2p,
    const float* __restrict__ b1, const float* __restrict__ Wl,
    float* __restrict__ P, int n) {
  __shared__ __align__(16) unsigned short sh_z[32 * 128];  // 8KB, swizzled
  __shared__ __align__(16) unsigned short sh1[32 * 264];   // 16.5KB (+8 pad)
  __shared__ float pacc[32][2];
  int rt0 = blockIdx.x * 2;
  int wave = threadIdx.x >> 6;
  int lane = threadIdx.x & 63;
  int quad = lane >> 4;
  if (threadIdx.x < 64) pacc[threadIdx.x >> 1][threadIdx.x & 1] = 0.f;

  // ---- phase 0: aggregate rows rt0*16 .. rt0*16+31 into sh_z ----
  {
    int g = lane >> 4;                         // edge slot 0..3
    int c = lane & 15;                         // 16B chunk 0..15
    unsigned cb = (unsigned)c << 4;
    int rbase = rt0 * 16;
    for (int it = 0; it < 8; ++it) {
      int rin = wave * 8 + it;                 // row in block 0..31
      int node = rbase + rin;
      f32x2 acc[4] = {};
      float d = 0.f;
      if (node < n) {
        d = dinv[node];
        int beg = offs[node], end = offs[node + 1];
        if (g == 0) {  // self loop: own pre-scaled row
          uint4 s = *reinterpret_cast<const uint4*>(
              Gb + (((unsigned)node << 8) | cb));
          acc[0] = (f32x2){bflo(s.x), bfhi(s.x)};
          acc[1] = (f32x2){bflo(s.y), bfhi(s.y)};
          acc[2] = (f32x2){bflo(s.z), bfhi(s.z)};
          acc[3] = (f32x2){bflo(s.w), bfhi(s.w)};
        }
        int e = beg + g;
        for (; e + 4 < end; e += 8) {  // two independent gathers in flight
          int i0 = ebuf[e], i1 = ebuf[e + 4];
          uint4 v0 = *reinterpret_cast<const uint4*>(
              Gb + (((unsigned)i0 << 8) | cb));
          uint4 v1 = *reinterpret_cast<const uint4*>(
              Gb + (((unsigned)i1 << 8) | cb));
          acc[0] += (f32x2){bflo(v0.x), bfhi(v0.x)};
          acc[1] += (f32x2){bflo(v0.y), bfhi(v0.y)};
          acc[2] += (f32x2){bflo(v0.z), bfhi(v0.z)};
          acc[3] += (f32x2){bflo(v0.w), bfhi(v0.w)};
          acc[0] += (f32x2){bflo(v1.x), bfhi(v1.x)};
          acc[1] += (f32x2){bflo(v1.y), bfhi(v1.y)};
          acc[2] += (f32x2){bflo(v1.z), bfhi(v1.z)};
          acc[3] += (f32x2){bflo(v1.w), bfhi(v1.w)};
        }
        if (e < end) {
          uint4 v0 = *reinterpret_cast<const uint4*>(
              Gb + (((unsigned)ebuf[e] << 8) | cb));
          acc[0] += (f32x2){bflo(v0.x), bfhi(v0.x)};
          acc[1] += (f32x2){bflo(v0.y), bfhi(v0.y)};
          acc[2] += (f32x2){bflo(v0.z), bfhi(v0.z)};
          acc[3] += (f32x2){bflo(v0.w), bfhi(v0.w)};
        }
      }
#pragma unroll
      for (int j = 0; j < 4; j++) {  // fold 4 edge-slots into lanes 0..15
        acc[j].x += __shfl_down(acc[j].x, 32);
        acc[j].y += __shfl_down(acc[j].y, 32);
        acc[j].x += __shfl_down(acc[j].x, 16);
        acc[j].y += __shfl_down(acc[j].y, 16);
      }
      if (g == 0) {
        unsigned o[4];
#pragma unroll
        for (int k = 0; k < 4; k++)
          o[k] = (unsigned)f2bf(acc[k].x * d) |
                 ((unsigned)f2bf(acc[k].y * d) << 16);
        int c_swz = c ^ (rin & 7);  // XOR-swizzle 16B chunks within row
        *reinterpret_cast<uint4*>(sh_z + rin * 128 + c_swz * 8) =
            *reinterpret_cast<uint4*>(o);
      }
    }
  }
  __syncthreads();

  // ---- phase A: h1 = relu(z@W1+b1), cols wave*64..+63, two 16-row tiles ----
  f32x4 acc[2][4] = {};
  int r0a = lane & 15;
  int xsw = lane & 7;  // (r0a&7) == ((16+r0a)&7)
#pragma unroll
  for (int ks = 0; ks < 4; ks++) {
    int cA = quad + ks * 4;
    int cS = (cA ^ xsw) * 8;
    short8 a0 = *reinterpret_cast<const short8*>(sh_z + r0a * 128 + cS);
    short8 a1 = *reinterpret_cast<const short8*>(sh_z + (16 + r0a) * 128 + cS);
#pragma unroll
    for (int ct = 0; ct < 4; ct++) {
      int nt = wave * 4 + ct;
      short8 b = *reinterpret_cast<const short8*>(
          B1p + ((size_t)(nt * 4 + ks) * 64 + lane) * 8);
      acc[0][ct] = __builtin_amdgcn_mfma_f32_16x16x32_bf16(a0, b, acc[0][ct], 0, 0, 0);
      acc[1][ct] = __builtin_amdgcn_mfma_f32_16x16x32_bf16(a1, b, acc[1][ct], 0, 0, 0);
    }
  }
#pragma unroll
  for (int ct = 0; ct < 4; ct++) {
    int c = (wave * 4 + ct) * 16 + (lane & 15);
    float bv = b1[c];
#pragma unroll
    for (int rg = 0; rg < 2; rg++)
#pragma unroll
      for (int i = 0; i < 4; i++) {
        float v = fmaxf(acc[rg][ct][i] + bv, 0.f);
        sh1[(rg * 16 + quad * 4 + i) * 264 + c] = f2bf(v);
      }
  }
  __syncthreads();

  // ---- phase B: cols wave*32 .. wave*32+31, K=256 from LDS; project to p ----
  f32x4 acc2[2][2] = {};
  const unsigned short* a2_0 = sh1 + (size_t)(lane & 15) * 264 + quad * 8;
  const unsigned short* a2_1 = sh1 + (size_t)(16 + (lane & 15)) * 264 + quad * 8;
#pragma unroll
  for (int ks = 0; ks < 8; ks++) {
    short8 a0 = *reinterpret_cast<const short8*>(a2_0 + ks * 32);
    short8 a1 = *reinterpret_cast<const short8*>(a2_1 + ks * 32);
#pragma unroll
    for (int ct = 0; ct < 2; ct++) {
      int nt = wave * 2 + ct;
      short8 b = *reinterpret_cast<const short8*>(
          B2p + ((size_t)(nt * 8 + ks) * 64 + lane) * 8);
      acc2[0][ct] = __builtin_amdgcn_mfma_f32_16x16x32_bf16(a0, b, acc2[0][ct], 0, 0, 0);
      acc2[1][ct] = __builtin_amdgcn_mfma_f32_16x16x32_bf16(a1, b, acc2[1][ct], 0, 0, 0);
    }
  }
  float p1[2][4] = {}, p2[2][4] = {};
#pragma unroll
  for (int rg = 0; rg < 2; rg++) {
    int r0 = (rt0 + rg) * 16 + quad * 4;
    float dv[4];
#pragma unroll
    for (int i = 0; i < 4; i++) dv[i] = dinv[r0 + i];
#pragma unroll
    for (int ct = 0; ct < 2; ct++) {
      int c = (wave * 2 + ct) * 16 + (lane & 15);
      float wl1 = Wl[c], wl2 = Wl[128 + c];
#pragma unroll
      for (int i = 0; i < 4; i++) {
        float v = acc2[rg][ct][i] * dv[i];
        p1[rg][i] = fmaf(v, wl1, p1[rg][i]);
        p2[rg][i] = fmaf(v, wl2, p2[rg][i]);
      }
    }
  }
  // reduce over the 16 lanes of this quad (cols), then cross-wave via LDS
#pragma unroll
  for (int rg = 0; rg < 2; rg++)
#pragma unroll
    for (int i = 0; i < 4; i++) {
#pragma unroll
      for (int o = 8; o; o >>= 1) {
        p1[rg][i] += __shfl_xor(p1[rg][i], o);
        p2[rg][i] += __shfl_xor(p2[rg][i], o);
      }
    }
  if ((lane & 15) == 0) {
#pragma unroll
    for (int rg = 0; rg < 2; rg++)
#pragma unroll
      for (int i = 0; i < 4; i++) {
        int row = rg * 16 + quad * 4 + i;
        atomicAdd(&pacc[row][0], p1[rg][i]);
        atomicAdd(&pacc[row][1], p2[rg][i]);
      }
  }
  __syncthreads();
  if (threadIdx.x < 64) {
    int row = threadIdx.x >> 1, comp = threadIdx.x & 1;
    P[(size_t)(rt0 * 16 + row) * 2 + comp] = pacc[row][comp];
  }
}

// ---------------- scalar aggregation of projections ----------------
// 4 lanes per node (64 nodes/block): q[i] = dinv[i]*(p[i] + sum_in p[src])
__global__ __launch_bounds__(256) void k_agg_s(const float2* __restrict__ p,
                                               const int* __restrict__ offs,
                                               const int* __restrict__ ebuf,
                                               const float* __restrict__ dinv,
                                               float2* __restrict__ q, int n) {
  int i = blockIdx.x * 64 + (threadIdx.x >> 2);
  if (i >= n) return;
  int sub = threadIdx.x & 3;
  int beg = offs[i], end = offs[i + 1];
  float sx = 0.f, sy = 0.f;
  for (int e = beg + sub; e < end; e += 4) {
    float2 v = p[ebuf[e]];
    sx += v.x;
    sy += v.y;
  }
  sx += __shfl_down(sx, 2);
  sy += __shfl_down(sy, 2);
  sx += __shfl_down(sx, 1);
  sy += __shfl_down(sy, 1);
  if (sub == 0) {
    float2 self = p[i];
    float d = dinv[i];
    q[i] = make_float2((sx + self.x) * d, (sy + self.y) * d);
  }
}

// ---------------- link head: sigmoid(q1[m0] + q2[m1] + C) ----------------
__global__ __launch_bounds__(256) void k_head2(const float2* __restrict__ q,
                                               const int* __restrict__ mask,
                                               const float* __restrict__ Cbuf,
                                               float* __restrict__ out, int P) {
  int p = blockIdx.x * 256 + threadIdx.x;
  if (p >= P) return;
  int m0 = mask[2 * p], m1 = mask[2 * p + 1];
  float s = q[m0].x + q[m1].y + Cbuf[0];
  out[p] = 1.0f / (1.0f + expf(-s));
}

extern "C" void kernel_launch(void* const* d_in, const int* in_sizes, int n_in,
                              void* d_out, int out_size, void* d_ws,
                              size_t ws_size, hipStream_t stream) {
  const int* edge = (const int*)d_in[0];
  const float* feat = (const float*)d_in[1];
  const int* mask = (const int*)d_in[2];
  const float* W1 = (const float*)d_in[3];
  const float* b1 = (const float*)d_in[4];
  const float* W2 = (const float*)d_in[5];
  const float* b2 = (const float*)d_in[6];
  const float* Wl = (const float*)d_in[7];
  const float* bl = (const float*)d_in[8];
  float* out = (float*)d_out;

  const int E = in_sizes[0] / 2;
  const int N = in_sizes[1] / NFEAT;  // must be <= 65536 (16-bit packing)
  const int P = in_sizes[2] / 2;
  const int* rowp = edge;
  const int* colp = edge + E;
  const int nrt = N / 16;             // 3125 for N=50000
  const int nb = (N + 63) / 64;       // 782 buckets (<= 1024 required)
  const int S = nb * NBLK;            // 100096 hist entries
  const int nS = (S + 255) / 256;     // 392 scan chunks (<= 1024 required)

  auto aln = [](size_t x) { return (x + 255) & ~(size_t)255; };
  char* w = (char*)d_ws;
  int* hist2d = (int*)w;           w += aln((size_t)S * 4);
  int* sbase = (int*)w;            w += aln((size_t)S * 4);
  int* psum = (int*)w;             w += aln((size_t)1024 * 4);
  float* Cbuf = (float*)w;         w += aln(256);
  int* offs = (int*)w;             w += aln((size_t)(N + 1) * 4);
  int* ebuf = (int*)w;             w += aln((size_t)E * 4);
  unsigned* tmp = (unsigned*)w;    w += aln((size_t)E * 4);
  float* dinv = (float*)w;         w += aln((size_t)N * 4 + 1024);
  unsigned short* xs = (unsigned short*)w;  w += aln((size_t)N * NFEAT * 2);
  float* p = (float*)w;            w += aln((size_t)(N + 32) * 8);
  float2* q = (float2*)w;          w += aln((size_t)N * 8);
  unsigned short* W1p = (unsigned short*)w; w += aln((size_t)NFEAT * NHID * 2);
  unsigned short* W2p = (unsigned short*)w; w += aln((size_t)NHID * NFEAT * 2);

  // ---- CSR build: deterministic 2-pass partition (+ W pack on spare blocks)
  k_hist_pack<<<NBLK + 8, 1024, 0, stream>>>(colp, hist2d, E, nb, W1, W2, W1p,
                                             W2p);
  k_bsum<<<nS + 1, 256, 0, stream>>>(hist2d, psum, S, b2, Wl, bl, Cbuf);
  k_s3m<<<nS, 256, 0, stream>>>(hist2d, psum, sbase, S);
  k_part2<<<NBLK, 1024, 0, stream>>>(rowp, colp, sbase, tmp, E, nb);
  // bsort + per-bucket cvt: ebuf/offs/dinv + xs = bf16(dinv * X)
  k_bsort_cvt<<<nb, 256, 0, stream>>>(tmp, sbase, ebuf, offs, dinv, feat, xs,
                                      N, E, nb);
  // fused: per block, aggregate 32 rows (z in LDS only) then
  // p[i] = {(dinv_i*(relu(z@W1+b1)@W2)_i) . Wl_lo, . Wl_hi}
  k_fused<<<(nrt + 1) / 2, 256, 0, stream>>>((const char*)xs, offs, ebuf, dinv,
                                             W1p, W2p, b1, Wl, p, N);
  // q[i] = dinv[i]*(p[i] + sum_in p[src])
  k_agg_s<<<(N + 63) / 64, 256, 0, stream>>>((const float2*)p, offs, ebuf,
                                             dinv, q, N);
  // head: out = sigmoid(q1[m0] + q2[m1] + C)
  k_head2<<<(P + 255) / 256, 256, 0, stream>>>(q, mask, Cbuf, out, P);
}

// Round 4
// 179.469 us; speedup vs baseline: 1.2916x; 1.0069x over previous
//
#include <hip/hip_runtime.h>
#include <math.h>

#define NFEAT 128
#define NHID 256
#define NBLK 256  // partition blocks; (block,bucket) segment avg = 4 edges

typedef __attribute__((ext_vector_type(8))) short short8;
typedef __attribute__((ext_vector_type(4))) float f32x4;
typedef __attribute__((ext_vector_type(2))) float f32x2;

__device__ inline unsigned short f2bf(float f) {
  unsigned u = __float_as_uint(f);
  u += 0x7fffu + ((u >> 16) & 1u);
  return (unsigned short)(u >> 16);
}
__device__ inline float bflo(unsigned u) { return __uint_as_float(u << 16); }
__device__ inline float bfhi(unsigned u) { return __uint_as_float(u & 0xffff0000u); }

// ============ CSR build: deterministic 2-pass partition, no global atomics ==
// bucket = dest >> 6 (64 nodes/bucket); needs N <= 65536 (16-bit packing)

// ---- per-(block,bucket) histogram (blocks 0..NBLK-1) + W-pack (blocks >= NBLK)
__device__ inline void packOne(const float* __restrict__ W,
                               unsigned short* __restrict__ Wp, int idx, int KS,
                               int OUT) {
  int lane = idx & 63;
  int t = idx >> 6;
  int ks = t % KS;
  int nt = t / KS;
  int n = nt * 16 + (lane & 15);
  int k0 = ks * 32 + (lane >> 4) * 8;
  unsigned short v[8];
#pragma unroll
  for (int j = 0; j < 8; j++) v[j] = f2bf(W[(size_t)(k0 + j) * OUT + n]);
  *reinterpret_cast<short8*>(Wp + (size_t)idx * 8) =
      *reinterpret_cast<short8*>(v);
}

__global__ __launch_bounds__(1024) void k_hist_pack(
    const int* __restrict__ col, int* __restrict__ hist2d, int nE, int nb,
    const float* __restrict__ W1, const float* __restrict__ W2,
    unsigned short* __restrict__ W1p, unsigned short* __restrict__ W2p) {
  if (blockIdx.x >= NBLK) {  // pack blocks: 8 x 1024 threads = 8192 items
    int idx = (blockIdx.x - NBLK) * 1024 + threadIdx.x;
    if (idx < 4096) packOne(W1, W1p, idx, 4, 256);
    else packOne(W2, W2p, idx - 4096, 8, 128);
    return;
  }
  __shared__ int h[1024];
  for (int i = threadIdx.x; i < nb; i += 1024) h[i] = 0;
  __syncthreads();
  int chunk = (nE + NBLK - 1) / NBLK;
  int beg = blockIdx.x * chunk, end = min(beg + chunk, nE);
  for (int e = beg + threadIdx.x; e < end; e += 1024)
    atomicAdd(&h[col[e] >> 6], 1);
  __syncthreads();
  for (int i = threadIdx.x; i < nb; i += 1024)
    hist2d[i * NBLK + blockIdx.x] = h[i];
}

// ---- scan phase 1: per-256-chunk sums; last block computes head constant ----
__global__ __launch_bounds__(256) void k_bsum(const int* __restrict__ a,
                                              int* __restrict__ psum, int S,
                                              const float* __restrict__ b2,
                                              const float* __restrict__ Wl,
                                              const float* __restrict__ bl,
                                              float* __restrict__ Cbuf) {
  int t = threadIdx.x;
  if (blockIdx.x == gridDim.x - 1) {  // C = b2.(Wl_lo+Wl_hi) + bl
    float v = (t < 128) ? b2[t] * (Wl[t] + Wl[128 + t]) : 0.f;
#pragma unroll
    for (int o = 32; o; o >>= 1) v += __shfl_down(v, o);
    __shared__ float fw[4];
    if ((t & 63) == 0) fw[t >> 6] = v;
    __syncthreads();
    if (t == 0) Cbuf[0] = fw[0] + fw[1] + fw[2] + fw[3] + bl[0];
    return;
  }
  int i = blockIdx.x * 256 + t;
  int v = (i < S) ? a[i] : 0;
#pragma unroll
  for (int o = 32; o; o >>= 1) v += __shfl_down(v, o);
  __shared__ int ws[4];
  if ((t & 63) == 0) ws[t >> 6] = v;
  __syncthreads();
  if (t == 0) psum[blockIdx.x] = ws[0] + ws[1] + ws[2] + ws[3];
}

// ---- scan phase 2+3 merged: each block redundantly reduces psum[0..b) for
//      its base, then scans its own 256 elements ----
__global__ __launch_bounds__(256) void k_s3m(const int* __restrict__ a,
                                             const int* __restrict__ psum,
                                             int* __restrict__ out, int S) {
  __shared__ int sh[256];
  __shared__ int ws[4];
  int t = threadIdx.x;
  int b = blockIdx.x;
  int partial = 0;
  for (int i = t; i < b; i += 256) partial += psum[i];
#pragma unroll
  for (int o = 32; o; o >>= 1) partial += __shfl_down(partial, o);
  if ((t & 63) == 0) ws[t >> 6] = partial;
  int i = b * 256 + t;
  int d = (i < S) ? a[i] : 0;
  sh[t] = d;
  __syncthreads();
  int base = ws[0] + ws[1] + ws[2] + ws[3];
  for (int o = 1; o < 256; o <<= 1) {
    int u = (t >= o) ? sh[t - o] : 0;
    __syncthreads();
    sh[t] += u;
    __syncthreads();
  }
  if (i < S) out[i] = base + sh[t] - d;
}

// ---- partition: each block writes its own contiguous segments ----
__global__ __launch_bounds__(1024) void k_part2(const int* __restrict__ row,
                                                const int* __restrict__ col,
                                                const int* __restrict__ sbase,
                                                unsigned* __restrict__ tmp,
                                                int nE, int nb) {
  __shared__ int cur[1024];
  for (int i = threadIdx.x; i < nb; i += 1024)
    cur[i] = sbase[i * NBLK + blockIdx.x];
  __syncthreads();
  int chunk = (nE + NBLK - 1) / NBLK;
  int beg = blockIdx.x * chunk, end = min(beg + chunk, nE);
  for (int e = beg + threadIdx.x; e < end; e += 1024) {
    int c = col[e];
    int pos = atomicAdd(&cur[c >> 6], 1);
    tmp[pos] = ((unsigned)(c & 63) << 16) | (unsigned)row[e];
  }
}

// ---- per-bucket counting sort -> ebuf + offs + dinv; also cvt this bucket's
//      64 feature rows: xs = bf16(dinv[row] * X). Per-wave privatized bins. --
__global__ __launch_bounds__(256) void k_bsort_cvt(
    const unsigned* __restrict__ tmp, const int* __restrict__ sbase,
    int* __restrict__ ebuf, int* __restrict__ offs, float* __restrict__ dinv,
    const float* __restrict__ feat, unsigned short* __restrict__ xs, int n,
    int nE, int nb) {
  __shared__ int bins[4][64], cur4[4][64];
  __shared__ float sdinv[64];
  int b = blockIdx.x;
  int beg = sbase[b * NBLK];
  int end = (b == nb - 1) ? nE : sbase[(b + 1) * NBLK];
  int t = threadIdx.x;
  int w4 = t >> 6;
  if (t == 0 && b == nb - 1) offs[n] = nE;
  bins[w4][t & 63] = 0;
  __syncthreads();
  for (int i = beg + t; i < end; i += 256)
    atomicAdd(&bins[w4][tmp[i] >> 16], 1);
  __syncthreads();
  if (t < 64) {  // wave 0: exclusive scan of 64 bucket totals via shfl
    int b0 = bins[0][t], b1 = bins[1][t], b2 = bins[2][t], b3 = bins[3][t];
    int v = b0 + b1 + b2 + b3;
    int s = v;
#pragma unroll
    for (int o = 1; o < 64; o <<= 1) {
      int u = __shfl_up(s, o);
      if (t >= o) s += u;
    }
    int off = beg + s - v;
    cur4[0][t] = off;
    cur4[1][t] = off + b0;
    cur4[2][t] = off + b0 + b1;
    cur4[3][t] = off + b0 + b1 + b2;
    float dv = rsqrtf((float)(v + 1));  // +1 self loop
    sdinv[t] = dv;
    int node = b * 64 + t;
    if (node < n) {
      offs[node] = off;
      dinv[node] = dv;
    }
  }
  __syncthreads();
  for (int i = beg + t; i < end; i += 256) {
    unsigned p = tmp[i];
    int pos = atomicAdd(&cur4[w4][p >> 16], 1);
    ebuf[pos] = (int)(p & 0xffffu);
  }
  // cvt: 64 rows x 32 float4
  for (int i = t; i < 64 * 32; i += 256) {
    int r = i >> 5;
    int node = b * 64 + r;
    if (node >= n) break;
    float d = sdinv[r];
    float4 v = reinterpret_cast<const float4*>(feat)[(size_t)node * 32 + (i & 31)];
    unsigned short o[4] = {f2bf(v.x * d), f2bf(v.y * d), f2bf(v.z * d),
                           f2bf(v.w * d)};
    reinterpret_cast<ushort4*>(xs)[(size_t)node * 32 + (i & 31)] =
        *reinterpret_cast<ushort4*>(o);
  }
}

// ======== FUSED: gather-aggregate (phase 0) + double GEMM + projection ======
// Block = 32 output rows. Phase 0: wave aggregates its 8 rows 2-at-a-time
// (4 edge-slots x 16 chunks, 4 gathers in flight/lane), writes bf16 rows into
// the first 8KB of the UNION LDS buffer (XOR-swizzled). Phase A: fragments
// register-staged, barrier, then h1 = relu(z@W1+b1) overwrites the union
// buffer (stride 264). Phase B: (h1@W2)*dinv projected to p. LDS = 17KB.
__global__ __launch_bounds__(256) void k_fused(
    const char* __restrict__ Gb, const int* __restrict__ offs,
    const int* __restrict__ ebuf, const float* __restrict__ dinv,
    const unsigned short* __restrict__ B1p, const unsigned short* __restrict__ B2p,
    const float* __restrict__ b1, const float* __restrict__ Wl,
    float* __restrict__ P, int n) {
  __shared__ __align__(16) unsigned short sh[32 * 264];  // union z(8KB)/h1
  __shared__ float pacc[32][2];
  int rt0 = blockIdx.x * 2;
  int wave = threadIdx.x >> 6;
  int lane = threadIdx.x & 63;
  int quad = lane >> 4;
  if (threadIdx.x < 64) pacc[threadIdx.x >> 1][threadIdx.x & 1] = 0.f;

  // ---- phase 0: aggregate rows rt0*16 .. rt0*16+31 into sh[0..8KB) ----
  {
    int g = lane >> 4;                 // edge slot 0..3
    int cidx = lane & 15;              // 16B chunk 0..15
    unsigned cb = (unsigned)cidx << 4;
    int rbase = rt0 * 16;
    for (int it = 0; it < 8; it += 2) {
      int rinA = wave * 8 + it, rinB = rinA + 1;
      int nodeA = rbase + rinA, nodeB = rbase + rinB;
      f32x2 aA[4] = {}, aB[4] = {};
      float dA = 0.f, dB = 0.f;
      int eA = 0, endA = 0, eB = 0, endB = 0;
      if (nodeA < n) {
        dA = dinv[nodeA];
        eA = offs[nodeA] + g;
        endA = offs[nodeA + 1];
        if (g == 0) {
          uint4 s = *reinterpret_cast<const uint4*>(
              Gb + (((unsigned)nodeA << 8) | cb));
          aA[0] = (f32x2){bflo(s.x), bfhi(s.x)};
          aA[1] = (f32x2){bflo(s.y), bfhi(s.y)};
          aA[2] = (f32x2){bflo(s.z), bfhi(s.z)};
          aA[3] = (f32x2){bflo(s.w), bfhi(s.w)};
        }
      }
      if (nodeB < n) {
        dB = dinv[nodeB];
        eB = offs[nodeB] + g;
        endB = offs[nodeB + 1];
        if (g == 0) {
          uint4 s = *reinterpret_cast<const uint4*>(
              Gb + (((unsigned)nodeB << 8) | cb));
          aB[0] = (f32x2){bflo(s.x), bfhi(s.x)};
          aB[1] = (f32x2){bflo(s.y), bfhi(s.y)};
          aB[2] = (f32x2){bflo(s.z), bfhi(s.z)};
          aB[3] = (f32x2){bflo(s.w), bfhi(s.w)};
        }
      }
      // joint loop: 4 independent gathers in flight (2 rows x 2-deep)
      while (eA + 4 < endA && eB + 4 < endB) {
        int i0 = ebuf[eA], i1 = ebuf[eA + 4];
        int j0 = ebuf[eB], j1 = ebuf[eB + 4];
        uint4 vA0 = *reinterpret_cast<const uint4*>(Gb + (((unsigned)i0 << 8) | cb));
        uint4 vA1 = *reinterpret_cast<const uint4*>(Gb + (((unsigned)i1 << 8) | cb));
        uint4 vB0 = *reinterpret_cast<const uint4*>(Gb + (((unsigned)j0 << 8) | cb));
        uint4 vB1 = *reinterpret_cast<const uint4*>(Gb + (((unsigned)j1 << 8) | cb));
        aA[0] += (f32x2){bflo(vA0.x), bfhi(vA0.x)};
        aA[1] += (f32x2){bflo(vA0.y), bfhi(vA0.y)};
        aA[2] += (f32x2){bflo(vA0.z), bfhi(vA0.z)};
        aA[3] += (f32x2){bflo(vA0.w), bfhi(vA0.w)};
        aA[0] += (f32x2){bflo(vA1.x), bfhi(vA1.x)};
        aA[1] += (f32x2){bflo(vA1.y), bfhi(vA1.y)};
        aA[2] += (f32x2){bflo(vA1.z), bfhi(vA1.z)};
        aA[3] += (f32x2){bflo(vA1.w), bfhi(vA1.w)};
        aB[0] += (f32x2){bflo(vB0.x), bfhi(vB0.x)};
        aB[1] += (f32x2){bflo(vB0.y), bfhi(vB0.y)};
        aB[2] += (f32x2){bflo(vB0.z), bfhi(vB0.z)};
        aB[3] += (f32x2){bflo(vB0.w), bfhi(vB0.w)};
        aB[0] += (f32x2){bflo(vB1.x), bfhi(vB1.x)};
        aB[1] += (f32x2){bflo(vB1.y), bfhi(vB1.y)};
        aB[2] += (f32x2){bflo(vB1.z), bfhi(vB1.z)};
        aB[3] += (f32x2){bflo(vB1.w), bfhi(vB1.w)};
        eA += 8;
        eB += 8;
      }
      for (; eA + 4 < endA; eA += 8) {
        int i0 = ebuf[eA], i1 = ebuf[eA + 4];
        uint4 v0 = *reinterpret_cast<const uint4*>(Gb + (((unsigned)i0 << 8) | cb));
        uint4 v1 = *reinterpret_cast<const uint4*>(Gb + (((unsigned)i1 << 8) | cb));
        aA[0] += (f32x2){bflo(v0.x), bfhi(v0.x)};
        aA[1] += (f32x2){bflo(v0.y), bfhi(v0.y)};
        aA[2] += (f32x2){bflo(v0.z), bfhi(v0.z)};
        aA[3] += (f32x2){bflo(v0.w), bfhi(v0.w)};
        aA[0] += (f32x2){bflo(v1.x), bfhi(v1.x)};
        aA[1] += (f32x2){bflo(v1.y), bfhi(v1.y)};
        aA[2] += (f32x2){bflo(v1.z), bfhi(v1.z)};
        aA[3] += (f32x2){bflo(v1.w), bfhi(v1.w)};
      }
      if (eA < endA) {
        uint4 v0 = *reinterpret_cast<const uint4*>(
            Gb + (((unsigned)ebuf[eA] << 8) | cb));
        aA[0] += (f32x2){bflo(v0.x), bfhi(v0.x)};
        aA[1] += (f32x2){bflo(v0.y), bfhi(v0.y)};
        aA[2] += (f32x2){bflo(v0.z), bfhi(v0.z)};
        aA[3] += (f32x2){bflo(v0.w), bfhi(v0.w)};
      }
      for (; eB + 4 < endB; eB += 8) {
        int i0 = ebuf[eB], i1 = ebuf[eB + 4];
        uint4 v0 = *reinterpret_cast<const uint4*>(Gb + (((unsigned)i0 << 8) | cb));
        uint4 v1 = *reinterpret_cast<const uint4*>(Gb + (((unsigned)i1 << 8) | cb));
        aB[0] += (f32x2){bflo(v0.x), bfhi(v0.x)};
        aB[1] += (f32x2){bflo(v0.y), bfhi(v0.y)};
        aB[2] += (f32x2){bflo(v0.z), bfhi(v0.z)};
        aB[3] += (f32x2){bflo(v0.w), bfhi(v0.w)};
        aB[0] += (f32x2){bflo(v1.x), bfhi(v1.x)};
        aB[1] += (f32x2){bflo(v1.y), bfhi(v1.y)};
        aB[2] += (f32x2){bflo(v1.z), bfhi(v1.z)};
        aB[3] += (f32x2){bflo(v1.w), bfhi(v1.w)};
      }
      if (eB < endB) {
        uint4 v0 = *reinterpret_cast<const uint4*>(
            Gb + (((unsigned)ebuf[eB] << 8) | cb));
        aB[0] += (f32x2){bflo(v0.x), bfhi(v0.x)};
        aB[1] += (f32x2){bflo(v0.y), bfhi(v0.y)};
        aB[2] += (f32x2){bflo(v0.z), bfhi(v0.z)};
        aB[3] += (f32x2){bflo(v0.w), bfhi(v0.w)};
      }
#pragma unroll
      for (int j = 0; j < 4; j++) {  // fold 4 edge-slots into lanes 0..15
        aA[j].x += __shfl_down(aA[j].x, 32);
        aA[j].y += __shfl_down(aA[j].y, 32);
        aB[j].x += __shfl_down(aB[j].x, 32);
        aB[j].y += __shfl_down(aB[j].y, 32);
        aA[j].x += __shfl_down(aA[j].x, 16);
        aA[j].y += __shfl_down(aA[j].y, 16);
        aB[j].x += __shfl_down(aB[j].x, 16);
        aB[j].y += __shfl_down(aB[j].y, 16);
      }
      if (g == 0) {
        unsigned oA[4], oB[4];
#pragma unroll
        for (int k = 0; k < 4; k++) {
          oA[k] = (unsigned)f2bf(aA[k].x * dA) |
                  ((unsigned)f2bf(aA[k].y * dA) << 16);
          oB[k] = (unsigned)f2bf(aB[k].x * dB) |
                  ((unsigned)f2bf(aB[k].y * dB) << 16);
        }
        *reinterpret_cast<uint4*>(sh + rinA * 128 + (cidx ^ (rinA & 7)) * 8) =
            *reinterpret_cast<uint4*>(oA);
        *reinterpret_cast<uint4*>(sh + rinB * 128 + (cidx ^ (rinB & 7)) * 8) =
            *reinterpret_cast<uint4*>(oB);
      }
    }
  }
  __syncthreads();

  // ---- phase A prologue: register-stage z fragments, then free the LDS ----
  int r0a = lane & 15;
  int xsw = lane & 7;  // (r0a&7) == ((16+r0a)&7)
  short8 fa0[4], fa1[4];
#pragma unroll
  for (int ks = 0; ks < 4; ks++) {
    int cS = ((quad + ks * 4) ^ xsw) * 8;
    fa0[ks] = *reinterpret_cast<const short8*>(sh + r0a * 128 + cS);
    fa1[ks] = *reinterpret_cast<const short8*>(sh + (16 + r0a) * 128 + cS);
  }
  __syncthreads();  // all z reads done; sh may be overwritten by h1

  // ---- phase A: h1 = relu(z@W1+b1), cols wave*64..+63, two 16-row tiles ----
  f32x4 acc[2][4] = {};
#pragma unroll
  for (int ks = 0; ks < 4; ks++) {
#pragma unroll
    for (int ct = 0; ct < 4; ct++) {
      int nt = wave * 4 + ct;
      short8 b = *reinterpret_cast<const short8*>(
          B1p + ((size_t)(nt * 4 + ks) * 64 + lane) * 8);
      acc[0][ct] = __builtin_amdgcn_mfma_f32_16x16x32_bf16(fa0[ks], b, acc[0][ct], 0, 0, 0);
      acc[1][ct] = __builtin_amdgcn_mfma_f32_16x16x32_bf16(fa1[ks], b, acc[1][ct], 0, 0, 0);
    }
  }
#pragma unroll
  for (int ct = 0; ct < 4; ct++) {
    int c = (wave * 4 + ct) * 16 + (lane & 15);
    float bv = b1[c];
#pragma unroll
    for (int rg = 0; rg < 2; rg++)
#pragma unroll
      for (int i = 0; i < 4; i++) {
        float v = fmaxf(acc[rg][ct][i] + bv, 0.f);
        sh[(rg * 16 + quad * 4 + i) * 264 + c] = f2bf(v);
      }
  }
  __syncthreads();

  // ---- phase B: cols wave*32 .. wave*32+31, K=256 from LDS; project to p ----
  f32x4 acc2[2][2] = {};
  const unsigned short* a2_0 = sh + (size_t)(lane & 15) * 264 + quad * 8;
  const unsigned short* a2_1 = sh + (size_t)(16 + (lane & 15)) * 264 + quad * 8;
#pragma unroll
  for (int ks = 0; ks < 8; ks++) {
    short8 a0 = *reinterpret_cast<const short8*>(a2_0 + ks * 32);
    short8 a1 = *reinterpret_cast<const short8*>(a2_1 + ks * 32);
#pragma unroll
    for (int ct = 0; ct < 2; ct++) {
      int nt = wave * 2 + ct;
      short8 b = *reinterpret_cast<const short8*>(
          B2p + ((size_t)(nt * 8 + ks) * 64 + lane) * 8);
      acc2[0][ct] = __builtin_amdgcn_mfma_f32_16x16x32_bf16(a0, b, acc2[0][ct], 0, 0, 0);
      acc2[1][ct] = __builtin_amdgcn_mfma_f32_16x16x32_bf16(a1, b, acc2[1][ct], 0, 0, 0);
    }
  }
  float p1[2][4] = {}, p2[2][4] = {};
#pragma unroll
  for (int rg = 0; rg < 2; rg++) {
    int r0 = (rt0 + rg) * 16 + quad * 4;
    float dv[4];
#pragma unroll
    for (int i = 0; i < 4; i++) dv[i] = dinv[r0 + i];
#pragma unroll
    for (int ct = 0; ct < 2; ct++) {
      int c = (wave * 2 + ct) * 16 + (lane & 15);
      float wl1 = Wl[c], wl2 = Wl[128 + c];
#pragma unroll
      for (int i = 0; i < 4; i++) {
        float v = acc2[rg][ct][i] * dv[i];
        p1[rg][i] = fmaf(v, wl1, p1[rg][i]);
        p2[rg][i] = fmaf(v, wl2, p2[rg][i]);
      }
    }
  }
  // reduce over the 16 lanes of this quad (cols), then cross-wave via LDS
#pragma unroll
  for (int rg = 0; rg < 2; rg++)
#pragma unroll
    for (int i = 0; i < 4; i++) {
#pragma unroll
      for (int o = 8; o; o >>= 1) {
        p1[rg][i] += __shfl_xor(p1[rg][i], o);
        p2[rg][i] += __shfl_xor(p2[rg][i], o);
      }
    }
  if ((lane & 15) == 0) {
#pragma unroll
    for (int rg = 0; rg < 2; rg++)
#pragma unroll
      for (int i = 0; i < 4; i++) {
        int row = rg * 16 + quad * 4 + i;
        atomicAdd(&pacc[row][0], p1[rg][i]);
        atomicAdd(&pacc[row][1], p2[rg][i]);
      }
  }
  __syncthreads();
  if (threadIdx.x < 64) {
    int row = threadIdx.x >> 1, comp = threadIdx.x & 1;
    P[(size_t)(rt0 * 16 + row) * 2 + comp] = pacc[row][comp];
  }
}

// ---------------- scalar aggregation of projections ----------------
// 4 lanes per node (64 nodes/block): q[i] = dinv[i]*(p[i] + sum_in p[src])
__global__ __launch_bounds__(256) void k_agg_s(const float2* __restrict__ p,
                                               const int* __restrict__ offs,
                                               const int* __restrict__ ebuf,
                                               const float* __restrict__ dinv,
                                               float2* __restrict__ q, int n) {
  int i = blockIdx.x * 64 + (threadIdx.x >> 2);
  if (i >= n) return;
  int sub = threadIdx.x & 3;
  int beg = offs[i], end = offs[i + 1];
  float sx = 0.f, sy = 0.f;
  for (int e = beg + sub; e < end; e += 4) {
    float2 v = p[ebuf[e]];
    sx += v.x;
    sy += v.y;
  }
  sx += __shfl_down(sx, 2);
  sy += __shfl_down(sy, 2);
  sx += __shfl_down(sx, 1);
  sy += __shfl_down(sy, 1);
  if (sub == 0) {
    float2 self = p[i];
    float d = dinv[i];
    q[i] = make_float2((sx + self.x) * d, (sy + self.y) * d);
  }
}

// ---------------- link head: sigmoid(q1[m0] + q2[m1] + C) ----------------
__global__ __launch_bounds__(256) void k_head2(const float2* __restrict__ q,
                                               const int* __restrict__ mask,
                                               const float* __restrict__ Cbuf,
                                               float* __restrict__ out, int P) {
  int p = blockIdx.x * 256 + threadIdx.x;
  if (p >= P) return;
  int m0 = mask[2 * p], m1 = mask[2 * p + 1];
  float s = q[m0].x + q[m1].y + Cbuf[0];
  out[p] = 1.0f / (1.0f + expf(-s));
}

extern "C" void kernel_launch(void* const* d_in, const int* in_sizes, int n_in,
                              void* d_out, int out_size, void* d_ws,
                              size_t ws_size, hipStream_t stream) {
  const int* edge = (const int*)d_in[0];
  const float* feat = (const float*)d_in[1];
  const int* mask = (const int*)d_in[2];
  const float* W1 = (const float*)d_in[3];
  const float* b1 = (const float*)d_in[4];
  const float* W2 = (const float*)d_in[5];
  const float* b2 = (const float*)d_in[6];
  const float* Wl = (const float*)d_in[7];
  const float* bl = (const float*)d_in[8];
  float* out = (float*)d_out;

  const int E = in_sizes[0] / 2;
  const int N = in_sizes[1] / NFEAT;  // must be <= 65536 (16-bit packing)
  const int P = in_sizes[2] / 2;
  const int* rowp = edge;
  const int* colp = edge + E;
  const int nrt = N / 16;             // 3125 for N=50000
  const int nb = (N + 63) / 64;       // 782 buckets (<= 1024 required)
  const int S = nb * NBLK;            // 200192 hist entries
  const int nS = (S + 255) / 256;     // 782 scan chunks (<= 1024 required)

  auto aln = [](size_t x) { return (x + 255) & ~(size_t)255; };
  char* w = (char*)d_ws;
  int* hist2d = (int*)w;           w += aln((size_t)S * 4);
  int* sbase = (int*)w;            w += aln((size_t)S * 4);
  int* psum = (int*)w;             w += aln((size_t)1024 * 4);
  float* Cbuf = (float*)w;         w += aln(256);
  int* offs = (int*)w;             w += aln((size_t)(N + 1) * 4);
  int* ebuf = (int*)w;             w += aln((size_t)E * 4);
  unsigned* tmp = (unsigned*)w;    w += aln((size_t)E * 4);
  float* dinv = (float*)w;         w += aln((size_t)N * 4 + 1024);
  unsigned short* xs = (unsigned short*)w;  w += aln((size_t)N * NFEAT * 2);
  float* p = (float*)w;            w += aln((size_t)(N + 32) * 8);
  float2* q = (float2*)w;          w += aln((size_t)N * 8);
  unsigned short* W1p = (unsigned short*)w; w += aln((size_t)NFEAT * NHID * 2);
  unsigned short* W2p = (unsigned short*)w; w += aln((size_t)NHID * NFEAT * 2);

  // ---- CSR build: deterministic 2-pass partition (+ W pack on spare blocks)
  k_hist_pack<<<NBLK + 8, 1024, 0, stream>>>(colp, hist2d, E, nb, W1, W2, W1p,
                                             W2p);
  k_bsum<<<nS + 1, 256, 0, stream>>>(hist2d, psum, S, b2, Wl, bl, Cbuf);
  k_s3m<<<nS, 256, 0, stream>>>(hist2d, psum, sbase, S);
  k_part2<<<NBLK, 1024, 0, stream>>>(rowp, colp, sbase, tmp, E, nb);
  // bsort + per-bucket cvt: ebuf/offs/dinv + xs = bf16(dinv * X)
  k_bsort_cvt<<<nb, 256, 0, stream>>>(tmp, sbase, ebuf, offs, dinv, feat, xs,
                                      N, E, nb);
  // fused: per block, aggregate 32 rows (z in LDS only) then
  // p[i] = {(dinv_i*(relu(z@W1+b1)@W2)_i) . Wl_lo, . Wl_hi}
  k_fused<<<(nrt + 1) / 2, 256, 0, stream>>>((const char*)xs, offs, ebuf, dinv,
                                             W1p, W2p, b1, Wl, p, N);
  // q[i] = dinv[i]*(p[i] + sum_in p[src])
  k_agg_s<<<(N + 63) / 64, 256, 0, stream>>>((const float2*)p, offs, ebuf,
                                             dinv, q, N);
  // head: out = sigmoid(q1[m0] + q2[m1] + C)
  k_head2<<<(P + 255) / 256, 256, 0, stream>>>(q, mask, Cbuf, out, P);
}